// Round 12
// baseline (67.317 us; speedup 1.0000x reference)
//
#include <hip/hip_runtime.h>
#include <hip/hip_fp16.h>

#define N_NODES 100000
#define N_EDGES 600000
#define DIM 128
#define HID 64
#define NTILES 6250          // 100000 / 16 exact

typedef __attribute__((ext_vector_type(8))) _Float16 half8;
typedef __attribute__((ext_vector_type(4))) _Float16 half4v;
typedef __attribute__((ext_vector_type(4))) float floatx4;
typedef __attribute__((ext_vector_type(4))) unsigned int uint4v;

// ---------------------------------------------------------------------------
// Kernel 0: W1T[c][k] (f16, [128][128]) = c<64 ? W1[k][c] : W1[128+k][c-64]
// ---------------------------------------------------------------------------
__global__ __launch_bounds__(256) void prep_W(
    const float* __restrict__ W1, __half* __restrict__ W1T)
{
    const int o = (int)(blockIdx.x * blockDim.x + threadIdx.x) * 2;
    if (o >= 128 * 128) return;
    const int c = o >> 7, k = o & 127;
    float w0, w1;
    if (c < HID) { w0 = W1[k * HID + c];               w1 = W1[(k + 1) * HID + c]; }
    else         { w0 = W1[(DIM + k) * HID + c - HID]; w1 = W1[(DIM + k + 1) * HID + c - HID]; }
    W1T[o]     = __float2half(w0);
    W1T[o + 1] = __float2half(w1);
}

// ---------------------------------------------------------------------------
// Kernel 1 (v7): pure-TLP, no LDS, no barriers. One wave per 16-row tile;
// A-fragments loaded directly global->reg (natural MFMA layout), converted
// to f16 once and pinned; two column-half passes with wf[4][4] pinned
// (32 VGPR each, from L2-hot W1T). Permuted packed epilogue as R5:
// hidden h=(2m+t)*16+4q+i stored at byte m*64+q*16+(t*4+i)*2 of node row.
// ~90-110 VGPR -> 4 waves/SIMD, 16 waves/CU; latency hidden by TLP.
// ---------------------------------------------------------------------------
__global__ __launch_bounds__(256) void precompute_P(
    const float* __restrict__ node_emb,
    const __half* __restrict__ W1T,
    const float* __restrict__ b1,
    __half* __restrict__ P)
{
    const int gwid = (int)(blockIdx.x * 4 + (threadIdx.x >> 6));
    if (gwid >= NTILES) return;
    const int lane = threadIdx.x & 63;
    const int lr   = lane & 15;
    const int q    = lane >> 4;

    // A-fragments: row gwid*16+lr, k = ks*32 + q*8 + 0..7  (8 x 16B loads)
    const float* arow = node_emb + (size_t)(gwid * 16 + lr) * DIM + q * 8;
    float4 a0[4], a1[4];
#pragma unroll
    for (int ks = 0; ks < 4; ks++) {
        a0[ks] = *(const float4*)(arow + ks * 32);
        a1[ks] = *(const float4*)(arow + ks * 32 + 4);
    }
    half8 af[4];
#pragma unroll
    for (int ks = 0; ks < 4; ks++) {
        half8 h;
        h[0] = (_Float16)a0[ks].x; h[1] = (_Float16)a0[ks].y;
        h[2] = (_Float16)a0[ks].z; h[3] = (_Float16)a0[ks].w;
        h[4] = (_Float16)a1[ks].x; h[5] = (_Float16)a1[ks].y;
        h[6] = (_Float16)a1[ks].z; h[7] = (_Float16)a1[ks].w;
        af[ks] = h;
    }
    // PIN af: prevent rematerialization (keeps f32 temps dead, af resident)
#pragma unroll
    for (int ks = 0; ks < 4; ks++) {
        uint4v t = __builtin_bit_cast(uint4v, af[ks]);
        asm volatile("" : "+v"(t));
        af[ks] = __builtin_bit_cast(half8, t);
    }

    char* prow = (char*)P + (size_t)(gwid * 16 + lr) * 256;

#pragma unroll 1
    for (int h = 0; h < 2; h++) {            // column half h: cols h*64..+63
        half8 wf[4][4];
#pragma unroll
        for (int nt = 0; nt < 4; nt++)
#pragma unroll
            for (int ks = 0; ks < 4; ks++)
                wf[nt][ks] = *(const half8*)(W1T + (size_t)(h * 64 + nt * 16 + lr) * 128 + ks * 32 + q * 8);
        // PIN wf
#pragma unroll
        for (int nt = 0; nt < 4; nt++)
#pragma unroll
            for (int ks = 0; ks < 4; ks++) {
                uint4v t = __builtin_bit_cast(uint4v, wf[nt][ks]);
                asm volatile("" : "+v"(t));
                wf[nt][ks] = __builtin_bit_cast(half8, t);
            }

        floatx4 acc[4];
#pragma unroll
        for (int nt = 0; nt < 4; nt++) acc[nt] = (floatx4){0.f, 0.f, 0.f, 0.f};

#pragma unroll
        for (int ks = 0; ks < 4; ks++)
#pragma unroll
            for (int nt = 0; nt < 4; nt++)
                acc[nt] = __builtin_amdgcn_mfma_f32_16x16x32_f16(wf[nt][ks], af[ks], acc[nt], 0, 0, 0);

#pragma unroll
        for (int mm = 0; mm < 2; mm++) {
            float va0 = acc[2 * mm][0], va1 = acc[2 * mm][1],
                  va2 = acc[2 * mm][2], va3 = acc[2 * mm][3];
            float vb0 = acc[2 * mm + 1][0], vb1 = acc[2 * mm + 1][1],
                  vb2 = acc[2 * mm + 1][2], vb3 = acc[2 * mm + 1][3];
            if (h == 0) {                    // bias only on hidden cols 0..63
                const float4 ba = *(const float4*)(b1 + (2 * mm) * 16 + q * 4);
                const float4 bb = *(const float4*)(b1 + (2 * mm + 1) * 16 + q * 4);
                va0 += ba.x; va1 += ba.y; va2 += ba.z; va3 += ba.w;
                vb0 += bb.x; vb1 += bb.y; vb2 += bb.z; vb3 += bb.w;
            }
            half8 hh;
            hh[0] = (_Float16)va0; hh[1] = (_Float16)va1;
            hh[2] = (_Float16)va2; hh[3] = (_Float16)va3;
            hh[4] = (_Float16)vb0; hh[5] = (_Float16)vb1;
            hh[6] = (_Float16)vb2; hh[7] = (_Float16)vb3;
            const int m = 2 * h + mm;
            *(half8*)(prow + m * 64 + q * 16) = hh;
        }
        __builtin_amdgcn_sched_barrier(0);   // keep halves separate (VGPR peak)
    }
}

// ---------------------------------------------------------------------------
__device__ inline bool detect_int64(const int* e32) {
    int orv = 0;
#pragma unroll
    for (int k = 0; k < 8; k++) orv |= e32[2 * k + 1];
    return orv == 0;
}

// ---------------------------------------------------------------------------
// Kernel 2 (R5 version, measured 22.1us): quarter-wave per edge, permuted
// W2, 16 edges per wave iteration.
// ---------------------------------------------------------------------------
__global__ __launch_bounds__(256) void edge_mlp(
    const __half* __restrict__ P,
    const void* __restrict__ eidx_raw,
    const float* __restrict__ W2,
    const float* __restrict__ b2,
    float* __restrict__ out)
{
    const int* e32 = (const int*)eidx_raw;
    const long long* e64 = (const long long*)eidx_raw;
    const bool is64 = detect_int64(e32);

    const int tid  = threadIdx.x;
    const int lane = tid & 63;
    const int j    = lane & 15;
    const int grp  = lane >> 4;
    const int hbase = ((j >> 3) << 5) + ((j & 1) << 4) + (((j >> 1) & 3) << 2);
    const float4 w2 = *(const float4*)(W2 + hbase);
    const float b2v = b2[0];

    const int gwid   = (int)((blockIdx.x * blockDim.x + tid) >> 6);
    const int nwaves = (int)((gridDim.x * blockDim.x) >> 6);

    const half4v zero = {(_Float16)0, (_Float16)0, (_Float16)0, (_Float16)0};

    for (int base = gwid * 16; base < N_EDGES; base += nwaves * 16) {
        int s[4], d[4];
#pragma unroll
        for (int u = 0; u < 4; u++) {
            const int e = base + 4 * u + grp;
            if (is64) { s[u] = (int)e64[e]; d[u] = (int)e64[N_EDGES + e]; }
            else      { s[u] = e32[e];      d[u] = e32[N_EDGES + e]; }
        }
        half4v av[4], bv[4];
#pragma unroll
        for (int u = 0; u < 4; u++) {
            av[u] = *(const half4v*)(P + (size_t)s[u] * 128 + 4 * j);
            bv[u] = *(const half4v*)(P + (size_t)d[u] * 128 + 64 + 4 * j);
        }
#pragma unroll
        for (int u = 0; u < 4; u++) {
            const half4v t = av[u] + bv[u];
            const half4v r = __builtin_elementwise_max(t, zero);
            float acc = (float)r[0] * w2.x + (float)r[1] * w2.y
                      + (float)r[2] * w2.z + (float)r[3] * w2.w;
#pragma unroll
            for (int off = 8; off >= 1; off >>= 1)
                acc += __shfl_xor(acc, off, 64);
            if (j == 0) out[base + 4 * u + grp] = acc + b2v;
        }
    }
}

// ---------------------------------------------------------------------------
// Fallback (ws too small): direct per-edge compute, slow but correct.
// ---------------------------------------------------------------------------
__global__ __launch_bounds__(256) void edge_mlp_direct(
    const float* __restrict__ node_emb,
    const void* __restrict__ eidx_raw,
    const float* __restrict__ W1,
    const float* __restrict__ b1,
    const float* __restrict__ W2,
    const float* __restrict__ b2,
    float* __restrict__ out)
{
    const int* e32 = (const int*)eidx_raw;
    const long long* e64 = (const long long*)eidx_raw;
    const bool is64 = detect_int64(e32);

    const int lane = threadIdx.x & 63;
    const float w2  = W2[lane];
    const float b2v = b2[0];
    const int gwid   = (int)((blockIdx.x * blockDim.x + threadIdx.x) >> 6);
    const int nwaves = (int)((gridDim.x * blockDim.x) >> 6);

    for (int e = gwid; e < N_EDGES; e += nwaves) {
        int s, d;
        if (is64) { s = (int)e64[e]; d = (int)e64[N_EDGES + e]; }
        else      { s = e32[e];      d = e32[N_EDGES + e]; }
        const float* es = node_emb + (size_t)s * DIM;
        const float* ed = node_emb + (size_t)d * DIM;
        float acc = b1[lane];
        for (int k = 0; k < DIM; k++) {
            acc += es[k] * W1[k * HID + lane];
            acc += ed[k] * W1[(DIM + k) * HID + lane];
        }
        float t = fmaxf(acc, 0.f) * w2;
#pragma unroll
        for (int off = 32; off >= 1; off >>= 1)
            t += __shfl_xor(t, off, 64);
        if (lane == 0) out[e] = t + b2v;
    }
}

// ---------------------------------------------------------------------------
extern "C" void kernel_launch(void* const* d_in, const int* in_sizes, int n_in,
                              void* d_out, int out_size, void* d_ws, size_t ws_size,
                              hipStream_t stream) {
    const float* node_emb = (const float*)d_in[0];
    const void*  eidx     = d_in[1];
    const float* W1       = (const float*)d_in[2];
    const float* b1       = (const float*)d_in[3];
    const float* W2       = (const float*)d_in[4];
    const float* b2       = (const float*)d_in[5];
    float* out = (float*)d_out;

    const size_t wt_off = 32u * 1024 * 1024;
    const size_t need   = wt_off + 128 * 128 * sizeof(__half);

    if (ws_size >= need) {
        __half* P   = (__half*)d_ws;
        __half* W1T = (__half*)((char*)d_ws + wt_off);
        prep_W<<<32, 256, 0, stream>>>(W1, W1T);
        precompute_P<<<(NTILES + 3) / 4, 256, 0, stream>>>(node_emb, W1T, b1, P);
        edge_mlp<<<2048, 256, 0, stream>>>(P, eidx, W2, b2, out);
    } else {
        edge_mlp_direct<<<4096, 256, 0, stream>>>(node_emb, eidx, W1, b1, W2, b2, out);
    }
}